// Round 9
// baseline (976.016 us; speedup 1.0000x reference)
//
#include <hip/hip_runtime.h>
#include <math.h>

#define M_ROWS 1536
#define NC 96
#define KG 16
#define FD 8192
#define NS 8
#define MARGIN 0.3f

#define KSPLIT 32
#define KCH 256            /* k per block */
#define BKS 32             /* k per stage */
#define NST (KCH / BKS)    /* 8 stages */
#define BN9 64             /* n cols per block */

// async global->LDS, 16B per lane (dest = wave-uniform base + lane*16)
__device__ __forceinline__ void gload16(const float* g, float* lds) {
    __builtin_amdgcn_global_load_lds(
        (const __attribute__((address_space(1))) void*)g,
        (__attribute__((address_space(3))) void*)lds, 16, 0, 0);
}

// ---------------- K1: centers + squared-norm partials ----------------
__global__ void centers_kernel(const float* __restrict__ feats,
                               float* __restrict__ centers,
                               float* __restrict__ fnp,   // [4][1536]
                               float* __restrict__ cnp) { // [4][96]
    const int c = blockIdx.x;
    const int bd = blockIdx.y;
    const int tid = threadIdx.x;

    float sq[KG];
#pragma unroll
    for (int k = 0; k < KG; ++k) sq[k] = 0.f;
    float cp = 0.f;

#pragma unroll
    for (int it = 0; it < 2; ++it) {
        const int base = bd * 2048 + it * 1024 + tid * 4;
        float4 acc = make_float4(0.f, 0.f, 0.f, 0.f);
#pragma unroll
        for (int k = 0; k < KG; ++k) {
            const float4 v = *(const float4*)&feats[(size_t)(c * KG + k) * FD + base];
            acc.x += v.x; acc.y += v.y; acc.z += v.z; acc.w += v.w;
            sq[k] += v.x * v.x + v.y * v.y + v.z * v.z + v.w * v.w;
        }
        float4 cv = make_float4(acc.x * 0.0625f, acc.y * 0.0625f,
                                acc.z * 0.0625f, acc.w * 0.0625f);
        *(float4*)&centers[(size_t)c * FD + base] = cv;
        cp += cv.x * cv.x + cv.y * cv.y + cv.z * cv.z + cv.w * cv.w;
    }

    const int lane = tid & 63;
    const int w = tid >> 6;
    __shared__ float wred[4][17];
#pragma unroll
    for (int k = 0; k < KG; ++k) {
        float v = sq[k];
#pragma unroll
        for (int off = 32; off > 0; off >>= 1) v += __shfl_down(v, off, 64);
        if (lane == 0) wred[w][k] = v;
    }
    {
        float v = cp;
#pragma unroll
        for (int off = 32; off > 0; off >>= 1) v += __shfl_down(v, off, 64);
        if (lane == 0) wred[w][16] = v;
    }
    __syncthreads();
    if (tid < 17) {
        const float t = wred[0][tid] + wred[1][tid] + wred[2][tid] + wred[3][tid];
        if (tid < 16) fnp[bd * M_ROWS + c * KG + tid] = t;
        else          cnp[bd * NC + c] = t;
    }
}

// ---------------- K2: dot(center, feat) partial GEMM ----------------
// R9: 768 blocks (24 n-tiles x 32 ks), bid%8==ks%8 pins k-slices to XCDs.
// __launch_bounds__(256,4) -> VGPR cap 128 -> 4 waves/SIMD bin (m69: occupancy
// quantum is power-of-2; VGPR 129..256 all land at 2 waves/SIMD). Natural live
// set ~130 so the squeeze is feasible (unlike R3/R4's 64-cap -> spill).
// LDS 2x(12+8)KB = 40KB -> 4 blocks/CU capacity -> 768 blocks = 3/CU resident,
// single round, 12 waves/CU. DMA staging, k-group-major linear slots.
__global__ __launch_bounds__(256, 4) void gemm9_kernel(const float* __restrict__ centers,
                                                       const float* __restrict__ feats,
                                                       float* __restrict__ part) { // [96][32][1536]
    const int bid = blockIdx.x;
    const int ks = bid & 31;
    const int nb = bid >> 5;
    const int tid = threadIdx.x;

    __shared__ float alds[2][NST * NC * 4];   // [kkg][96] float4 slots, 12 KB
    __shared__ float blds[2][NST * BN9 * 4];  // [kkg][64] float4 slots,  8 KB

    const int j0 = nb * BN9;
    const int k0b = ks * KCH;

    const int tx = tid & 15;         // n = tx + 16*nn, nn 0..3
    const int ty = tid >> 4;         // m = ty*6 + mi, mi 0..5
    const int m0 = ty * 6;

    // per-lane DMA source offsets (32-bit; only k0 varies per stage)
    int aoff[3], boff[2], albase[3], blbase[2];
#pragma unroll
    for (int i = 0; i < 3; ++i) {
        const int s = tid + i * 256;              // slot = kkg*96 + r
        const int kkg = s / NC, r = s - kkg * NC;
        aoff[i] = r * FD + kkg * 4;
        albase[i] = (i * 256 + (tid & 192)) * 4;  // float offset of wave chunk
    }
#pragma unroll
    for (int i = 0; i < 2; ++i) {
        const int s = tid + i * 256;              // slot = kkg*64 + n
        const int kkg = s >> 6, n = s & 63;
        boff[i] = (j0 + n) * FD + kkg * 4;
        blbase[i] = (i * 256 + (tid & 192)) * 4;
    }

    // prologue: stage 0 -> buf 0
#pragma unroll
    for (int i = 0; i < 3; ++i) gload16(centers + aoff[i] + k0b, &alds[0][albase[i]]);
#pragma unroll
    for (int i = 0; i < 2; ++i) gload16(feats + boff[i] + k0b, &blds[0][blbase[i]]);
    __syncthreads();

    float acc[6][4];
#pragma unroll
    for (int a = 0; a < 6; ++a)
#pragma unroll
        for (int b = 0; b < 4; ++b) acc[a][b] = 0.f;

    int cur = 0;
    for (int st = 0; st < NST; ++st) {
        // issue next stage's DMA into the other buffer; flies during compute
        if (st < NST - 1) {
            const int k0 = k0b + (st + 1) * BKS;
#pragma unroll
            for (int i = 0; i < 3; ++i) gload16(centers + aoff[i] + k0, &alds[cur ^ 1][albase[i]]);
#pragma unroll
            for (int i = 0; i < 2; ++i) gload16(feats + boff[i] + k0, &blds[cur ^ 1][blbase[i]]);
        }

        // compute current buffer: k-group-major, conflict-free reads
#pragma unroll
        for (int kg = 0; kg < NST; ++kg) {
            const float* ab = &alds[cur][kg * (NC * 4)];
            const float* bb = &blds[cur][kg * (BN9 * 4)];
            float4 bv[4];
#pragma unroll
            for (int nn = 0; nn < 4; ++nn)
                bv[nn] = *(const float4*)&bb[(tx + nn * 16) * 4];
#pragma unroll
            for (int mi = 0; mi < 6; ++mi) {
                const float4 a = *(const float4*)&ab[(m0 + mi) * 4];
#pragma unroll
                for (int nn = 0; nn < 4; ++nn)
                    acc[mi][nn] += a.x * bv[nn].x + a.y * bv[nn].y +
                                   a.z * bv[nn].z + a.w * bv[nn].w;
            }
        }
        __syncthreads();   // drains vmcnt -> next buffer ready
        cur ^= 1;
    }

#pragma unroll
    for (int mi = 0; mi < 6; ++mi) {
        float* row = part + ((size_t)(m0 + mi) * KSPLIT + ks) * M_ROWS + j0;
#pragma unroll
        for (int nn = 0; nn < 4; ++nn)
            row[tx + nn * 16] = acc[mi][nn];
    }
}

// ---------------- K3: finalize d2 + masked argmax/argmin ----------------
__global__ void select_kernel(const float* __restrict__ part,
                              const float* __restrict__ fnp,
                              const float* __restrict__ cnp,
                              const int* __restrict__ labels,
                              int* __restrict__ pinds,
                              int* __restrict__ ninds) {
    const int c = blockIdx.x;
    const int tid = threadIdx.x;
    const int anchor = labels[c * KG];

    float cn = 0.f;
#pragma unroll
    for (int b = 0; b < 4; ++b) cn += cnp[b * NC + c];

    float bestp = -INFINITY; int bpi = 1 << 30;
    float bestn =  INFINITY; int bni = 1 << 30;

    const float* pc = part + (size_t)c * KSPLIT * M_ROWS;
    for (int j = tid; j < M_ROWS; j += 256) {
        float dot = 0.f;
#pragma unroll
        for (int p = 0; p < KSPLIT; ++p)
            dot += pc[(size_t)p * M_ROWS + j];
        float fn = 0.f;
#pragma unroll
        for (int b = 0; b < 4; ++b) fn += fnp[b * M_ROWS + j];
        const float d2 = cn + fn - 2.f * dot;
        const bool pos = (labels[j] == anchor);
        if (pos) {
            if (d2 > bestp || (d2 == bestp && j < bpi)) { bestp = d2; bpi = j; }
        } else {
            if (d2 < bestn || (d2 == bestn && j < bni)) { bestn = d2; bni = j; }
        }
    }

    __shared__ float sv[256];
    __shared__ int   si[256];
    sv[tid] = bestp; si[tid] = bpi; __syncthreads();
    for (int s = 128; s > 0; s >>= 1) {
        if (tid < s) {
            if (sv[tid + s] > sv[tid] ||
                (sv[tid + s] == sv[tid] && si[tid + s] < si[tid])) {
                sv[tid] = sv[tid + s]; si[tid] = si[tid + s];
            }
        }
        __syncthreads();
    }
    if (tid == 0) pinds[c] = si[0];
    __syncthreads();
    sv[tid] = bestn; si[tid] = bni; __syncthreads();
    for (int s = 128; s > 0; s >>= 1) {
        if (tid < s) {
            if (sv[tid + s] < sv[tid] ||
                (sv[tid + s] == sv[tid] && si[tid + s] < si[tid])) {
                sv[tid] = sv[tid + s]; si[tid] = si[tid + s];
            }
        }
        __syncthreads();
    }
    if (tid == 0) ninds[c] = si[0];
}

// ---------------- K4: local stripe distances + DP ----------------
__global__ void local_kernel(const float* __restrict__ centers,
                             const float* __restrict__ localf,
                             const int* __restrict__ pinds,
                             const int* __restrict__ ninds,
                             float* __restrict__ res) { // [2][96]
    const int c = blockIdx.x;
    const int which = blockIdx.y;
    const int tid = threadIdx.x;
    const int idx = (which == 0) ? pinds[c] : ninds[c];

    __shared__ float xl[NS * 1028];
    __shared__ float yl[NS * 1032];
    __shared__ float sred[256];
    __shared__ float dmat[64];
    __shared__ float xx[8], yy[8], xyv[64];

#pragma unroll
    for (int it = 0; it < 8; ++it) {
        const int q = tid + it * 256;
        const float4 v = *(const float4*)&centers[(size_t)c * FD + q * 4];
        const int i = q >> 8;
        const int d = (q * 4) & 1023;
        *(float4*)&xl[i * 1028 + d] = v;

        const float4 w = *(const float4*)&localf[(size_t)idx * FD + q * 4];
        const int jb = (q * 4) & 7;
        const int dd = q >> 1;
        yl[(jb + 0) * 1032 + dd] = w.x;
        yl[(jb + 1) * 1032 + dd] = w.y;
        yl[(jb + 2) * 1032 + dd] = w.z;
        yl[(jb + 3) * 1032 + dd] = w.w;
    }
    __syncthreads();

    const int p = tid >> 2, c4 = tid & 3;
    const int i = p >> 3, j = p & 7;
    float s = 0.f;
    for (int t = 0; t < 64; ++t) {
        const int d = c4 * 4 + t * 16;
        const float4 xv = *(const float4*)&xl[i * 1028 + d];
        const float4 yv = *(const float4*)&yl[j * 1032 + d];
        s += xv.x * yv.x + xv.y * yv.y + xv.z * yv.z + xv.w * yv.w;
    }
    sred[tid] = s;
    __syncthreads();
    if (tid < 64)
        xyv[tid] = sred[tid * 4] + sred[tid * 4 + 1] + sred[tid * 4 + 2] + sred[tid * 4 + 3];

    float s2 = 0.f;
    if (tid < 64) {
        const int r = tid >> 2;
        const float* base = (r < 8) ? &xl[r * 1028] : &yl[(r - 8) * 1032];
        for (int t = 0; t < 64; ++t) {
            const int d = c4 * 4 + t * 16;
            const float4 v = *(const float4*)&base[d];
            s2 += v.x * v.x + v.y * v.y + v.z * v.z + v.w * v.w;
        }
    }
    __syncthreads();
    sred[tid] = s2;
    __syncthreads();
    if (tid < 16) {
        const float v = sred[tid * 4] + sred[tid * 4 + 1] + sred[tid * 4 + 2] + sred[tid * 4 + 3];
        if (tid < 8) xx[tid] = v; else yy[tid - 8] = v;
    }
    __syncthreads();

    if (tid < 64) {
        const float d2 = xx[i] + yy[j] - 2.f * xyv[tid];
        const float d = sqrtf(fmaxf(d2, 1e-12f));
        dmat[tid] = tanhf(0.5f * d);
    }
    __syncthreads();

    if (tid == 0) {
        float prev[8], cur[8];
        cur[0] = dmat[0];
#pragma unroll
        for (int jj = 1; jj < 8; ++jj) cur[jj] = cur[jj - 1] + dmat[jj];
        for (int ii = 1; ii < 8; ++ii) {
#pragma unroll
            for (int jj = 0; jj < 8; ++jj) prev[jj] = cur[jj];
            cur[0] = prev[0] + dmat[ii * 8];
#pragma unroll
            for (int jj = 1; jj < 8; ++jj)
                cur[jj] = fminf(prev[jj], cur[jj - 1]) + dmat[ii * 8 + jj];
        }
        res[which * NC + c] = cur[7];
    }
}

// ---------------- K5: mean(relu(ap - an + margin)) ----------------
__global__ void loss_kernel(const float* __restrict__ res, float* __restrict__ out) {
    const int tid = threadIdx.x; // 128
    float v = 0.f;
    if (tid < NC) v = fmaxf(res[tid] - res[NC + tid] + MARGIN, 0.f);
#pragma unroll
    for (int off = 32; off > 0; off >>= 1) v += __shfl_down(v, off, 64);
    __shared__ float w2[2];
    const int lane = tid & 63, w = tid >> 6;
    if (lane == 0) w2[w] = v;
    __syncthreads();
    if (tid == 0) out[0] = (w2[0] + w2[1]) * (1.f / NC);
}

extern "C" void kernel_launch(void* const* d_in, const int* in_sizes, int n_in,
                              void* d_out, int out_size, void* d_ws, size_t ws_size,
                              hipStream_t stream) {
    const float* feats  = (const float*)d_in[0];
    const int*   labels = (const int*)d_in[1];
    const float* localf = (const float*)d_in[2];
    float* out = (float*)d_out;

    float* centers = (float*)d_ws;                          // 96*8192
    float* part    = centers + (size_t)NC * FD;             // 96*32*1536
    float* fnp     = part + (size_t)NC * KSPLIT * M_ROWS;   // 4*1536
    float* cnp     = fnp + 4 * M_ROWS;                      // 4*96
    float* res     = cnp + 4 * NC;                          // 2*96
    int*   pinds   = (int*)(res + 2 * NC);                  // 96
    int*   ninds   = pinds + NC;                            // 96

    hipLaunchKernelGGL(centers_kernel, dim3(NC, 4), dim3(256), 0, stream,
                       feats, centers, fnp, cnp);
    hipLaunchKernelGGL(gemm9_kernel, dim3(24 * KSPLIT), dim3(256), 0, stream,
                       centers, feats, part);
    hipLaunchKernelGGL(select_kernel, dim3(NC), dim3(256), 0, stream,
                       part, fnp, cnp, labels, pinds, ninds);
    hipLaunchKernelGGL(local_kernel, dim3(NC, 2), dim3(256), 0, stream,
                       centers, localf, pinds, ninds, res);
    hipLaunchKernelGGL(loss_kernel, dim3(1), dim3(128), 0, stream, res, out);
}

// Round 10
// 53.797 us; speedup vs baseline: 18.1427x; 18.1427x over previous
//
#include <hip/hip_runtime.h>
#include <math.h>

#define M_ROWS 1536
#define NC 96
#define KG 16
#define FD 8192
#define NS 8
#define MARGIN 0.3f

#define KSPLIT 32
#define KCH 256            /* k per block */
#define BKS 32             /* k per stage */
#define NST (KCH / BKS)    /* 8 stages */
#define BN 64              /* n cols per block */

typedef short v8s __attribute__((ext_vector_type(8)));   // 8 bf16 (guide 3)
typedef float v4f __attribute__((ext_vector_type(4)));

__device__ __forceinline__ unsigned short f2bf(float x) {
    unsigned int u = __float_as_uint(x);
    return (unsigned short)((u + 0x7fffu + ((u >> 16) & 1u)) >> 16);  // RNE
}
__device__ __forceinline__ float bf2f(unsigned short h) {
    return __uint_as_float(((unsigned int)h) << 16);
}
__device__ __forceinline__ void split4(float4 v, ushort4* h, ushort4* l) {
    const unsigned short hx = f2bf(v.x), hy = f2bf(v.y), hz = f2bf(v.z), hw = f2bf(v.w);
    *h = make_ushort4(hx, hy, hz, hw);
    *l = make_ushort4(f2bf(v.x - bf2f(hx)), f2bf(v.y - bf2f(hy)),
                      f2bf(v.z - bf2f(hz)), f2bf(v.w - bf2f(hw)));
}

// ---------------- K1: centers + squared-norm partials ----------------
__global__ void centers_kernel(const float* __restrict__ feats,
                               float* __restrict__ centers,
                               float* __restrict__ fnp,   // [4][1536]
                               float* __restrict__ cnp) { // [4][96]
    const int c = blockIdx.x;
    const int bd = blockIdx.y;
    const int tid = threadIdx.x;

    float sq[KG];
#pragma unroll
    for (int k = 0; k < KG; ++k) sq[k] = 0.f;
    float cp = 0.f;

#pragma unroll
    for (int it = 0; it < 2; ++it) {
        const int base = bd * 2048 + it * 1024 + tid * 4;
        float4 acc = make_float4(0.f, 0.f, 0.f, 0.f);
#pragma unroll
        for (int k = 0; k < KG; ++k) {
            const float4 v = *(const float4*)&feats[(size_t)(c * KG + k) * FD + base];
            acc.x += v.x; acc.y += v.y; acc.z += v.z; acc.w += v.w;
            sq[k] += v.x * v.x + v.y * v.y + v.z * v.z + v.w * v.w;
        }
        float4 cv = make_float4(acc.x * 0.0625f, acc.y * 0.0625f,
                                acc.z * 0.0625f, acc.w * 0.0625f);
        *(float4*)&centers[(size_t)c * FD + base] = cv;
        cp += cv.x * cv.x + cv.y * cv.y + cv.z * cv.z + cv.w * cv.w;
    }

    const int lane = tid & 63;
    const int w = tid >> 6;
    __shared__ float wred[4][17];
#pragma unroll
    for (int k = 0; k < KG; ++k) {
        float v = sq[k];
#pragma unroll
        for (int off = 32; off > 0; off >>= 1) v += __shfl_down(v, off, 64);
        if (lane == 0) wred[w][k] = v;
    }
    {
        float v = cp;
#pragma unroll
        for (int off = 32; off > 0; off >>= 1) v += __shfl_down(v, off, 64);
        if (lane == 0) wred[w][16] = v;
    }
    __syncthreads();
    if (tid < 17) {
        const float t = wred[0][tid] + wred[1][tid] + wred[2][tid] + wred[3][tid];
        if (tid < 16) fnp[bd * M_ROWS + c * KG + tid] = t;
        else          cnp[bd * NC + c] = t;
    }
}

// ---------------- K2: bf16x3 MFMA partial GEMM ----------------
// 768 blocks = 24 nb x 32 ks (bid%8==ks%8 pins k-slice to one XCD), 4 waves.
// fp32 -> (hi,lo) bf16 split at staging; C = Ah*Bh + Ah*Bl + Al*Bh via
// mfma_f32_16x16x32_bf16 (fp32 acc) -> d2 error ~7e-4, selection-safe.
// LDS frag-linear: each 16x32 bf16 tile = 64 lanes x 16B; compute reads
// lds[lane*16] (conflict-free b128). Double-buffered, 1 barrier/stage.
// NO min-waves launch_bounds (R4/R9: it forces VGPR=64 -> spill).
__global__ __launch_bounds__(256) void gemm10_kernel(const float* __restrict__ centers,
                                                     const float* __restrict__ feats,
                                                     float* __restrict__ part) { // [96][32][1536]
    const int bid = blockIdx.x;
    const int ks = bid & 31;
    const int nb = bid >> 5;
    const int tid = threadIdx.x;
    const int j0 = nb * BN;
    const int k0b = ks * KCH;

    __shared__ unsigned short AH[2][6 * 512], AL[2][6 * 512];   // 6 m-tiles
    __shared__ unsigned short BH[2][4 * 512], BL[2][4 * 512];   // 4 n-tiles

    // staging maps: element (row r, k) -> tile rt=r>>4, lane l=(r&15)|((k>>3)<<4),
    // elem e=k&7. Thread's 4 consecutive k share (k>>3) -> one ushort4 write.
    int aoff[3], aidx[3];
#pragma unroll
    for (int i = 0; i < 3; ++i) {
        const int q = tid + i * 256;                 // A: 96 rows x 32 k / 4 = 768 f4
        const int m = q >> 3, kk = (q & 7) * 4;
        aoff[i] = m * FD + kk;
        aidx[i] = (m >> 4) * 512 + ((m & 15) | ((kk >> 3) << 4)) * 8 + (kk & 7);
    }
    int boff[2], bidx[2];
#pragma unroll
    for (int i = 0; i < 2; ++i) {
        const int q = tid + i * 256;                 // B: 64 rows x 32 k / 4 = 512 f4
        const int n = q >> 3, kk = (q & 7) * 4;
        boff[i] = (j0 + n) * FD + kk;
        bidx[i] = (n >> 4) * 512 + ((n & 15) | ((kk >> 3) << 4)) * 8 + (kk & 7);
    }

    float4 pa[3], pb[2];
    // prologue: stage 0 -> buf 0
#pragma unroll
    for (int i = 0; i < 3; ++i) pa[i] = *(const float4*)&centers[aoff[i] + k0b];
#pragma unroll
    for (int i = 0; i < 2; ++i) pb[i] = *(const float4*)&feats[boff[i] + k0b];
#pragma unroll
    for (int i = 0; i < 3; ++i) {
        ushort4 h, l; split4(pa[i], &h, &l);
        *(ushort4*)&AH[0][aidx[i]] = h; *(ushort4*)&AL[0][aidx[i]] = l;
    }
#pragma unroll
    for (int i = 0; i < 2; ++i) {
        ushort4 h, l; split4(pb[i], &h, &l);
        *(ushort4*)&BH[0][bidx[i]] = h; *(ushort4*)&BL[0][bidx[i]] = l;
    }
    __syncthreads();

    v4f acc[6];
#pragma unroll
    for (int t = 0; t < 6; ++t) { acc[t][0] = 0.f; acc[t][1] = 0.f; acc[t][2] = 0.f; acc[t][3] = 0.f; }

    const int w = tid >> 6, lane = tid & 63;
    const int fo = lane * 8;

    int cur = 0;
    for (int st = 0; st < NST; ++st) {
        // issue next stage's global loads; latency hides under MFMA below
        if (st < NST - 1) {
            const int k0 = k0b + (st + 1) * BKS;
#pragma unroll
            for (int i = 0; i < 3; ++i) pa[i] = *(const float4*)&centers[aoff[i] + k0];
#pragma unroll
            for (int i = 0; i < 2; ++i) pb[i] = *(const float4*)&feats[boff[i] + k0];
        }

        // compute current buffer: wave w -> n-tile w, 6 m-tiles, 3 mfma each
        const v8s Bhf = *(const v8s*)&BH[cur][w * 512 + fo];
        const v8s Blf = *(const v8s*)&BL[cur][w * 512 + fo];
#pragma unroll
        for (int mt = 0; mt < 6; ++mt) {
            const v8s Ahf = *(const v8s*)&AH[cur][mt * 512 + fo];
            const v8s Alf = *(const v8s*)&AL[cur][mt * 512 + fo];
            acc[mt] = __builtin_amdgcn_mfma_f32_16x16x32_bf16(Ahf, Bhf, acc[mt], 0, 0, 0);
            acc[mt] = __builtin_amdgcn_mfma_f32_16x16x32_bf16(Ahf, Blf, acc[mt], 0, 0, 0);
            acc[mt] = __builtin_amdgcn_mfma_f32_16x16x32_bf16(Alf, Bhf, acc[mt], 0, 0, 0);
        }

        // convert + write next stage into the other buffer
        if (st < NST - 1) {
            const int d = cur ^ 1;
#pragma unroll
            for (int i = 0; i < 3; ++i) {
                ushort4 h, l; split4(pa[i], &h, &l);
                *(ushort4*)&AH[d][aidx[i]] = h; *(ushort4*)&AL[d][aidx[i]] = l;
            }
#pragma unroll
            for (int i = 0; i < 2; ++i) {
                ushort4 h, l; split4(pb[i], &h, &l);
                *(ushort4*)&BH[d][bidx[i]] = h; *(ushort4*)&BL[d][bidx[i]] = l;
            }
        }
        __syncthreads();
        cur ^= 1;
    }

    // epilogue: C/D layout (m89-verified): col = lane&15, row = (lane>>4)*4 + j
    const int col = lane & 15, r0 = (lane >> 4) * 4;
    const int n = j0 + w * 16 + col;
#pragma unroll
    for (int mt = 0; mt < 6; ++mt) {
#pragma unroll
        for (int j = 0; j < 4; ++j) {
            const int m = mt * 16 + r0 + j;
            part[((size_t)m * KSPLIT + ks) * M_ROWS + n] = acc[mt][j];
        }
    }
}

// ---------------- K3: finalize d2 + masked argmax/argmin ----------------
__global__ void select_kernel(const float* __restrict__ part,
                              const float* __restrict__ fnp,
                              const float* __restrict__ cnp,
                              const int* __restrict__ labels,
                              int* __restrict__ pinds,
                              int* __restrict__ ninds) {
    const int c = blockIdx.x;
    const int tid = threadIdx.x;
    const int anchor = labels[c * KG];

    float cn = 0.f;
#pragma unroll
    for (int b = 0; b < 4; ++b) cn += cnp[b * NC + c];

    float bestp = -INFINITY; int bpi = 1 << 30;
    float bestn =  INFINITY; int bni = 1 << 30;

    const float* pc = part + (size_t)c * KSPLIT * M_ROWS;
    for (int j = tid; j < M_ROWS; j += 256) {
        float dot = 0.f;
#pragma unroll
        for (int p = 0; p < KSPLIT; ++p)
            dot += pc[(size_t)p * M_ROWS + j];
        float fn = 0.f;
#pragma unroll
        for (int b = 0; b < 4; ++b) fn += fnp[b * M_ROWS + j];
        const float d2 = cn + fn - 2.f * dot;
        const bool pos = (labels[j] == anchor);
        if (pos) {
            if (d2 > bestp || (d2 == bestp && j < bpi)) { bestp = d2; bpi = j; }
        } else {
            if (d2 < bestn || (d2 == bestn && j < bni)) { bestn = d2; bni = j; }
        }
    }

    __shared__ float sv[256];
    __shared__ int   si[256];
    sv[tid] = bestp; si[tid] = bpi; __syncthreads();
    for (int s = 128; s > 0; s >>= 1) {
        if (tid < s) {
            if (sv[tid + s] > sv[tid] ||
                (sv[tid + s] == sv[tid] && si[tid + s] < si[tid])) {
                sv[tid] = sv[tid + s]; si[tid] = si[tid + s];
            }
        }
        __syncthreads();
    }
    if (tid == 0) pinds[c] = si[0];
    __syncthreads();
    sv[tid] = bestn; si[tid] = bni; __syncthreads();
    for (int s = 128; s > 0; s >>= 1) {
        if (tid < s) {
            if (sv[tid + s] < sv[tid] ||
                (sv[tid + s] == sv[tid] && si[tid + s] < si[tid])) {
                sv[tid] = sv[tid + s]; si[tid] = si[tid + s];
            }
        }
        __syncthreads();
    }
    if (tid == 0) ninds[c] = si[0];
}

// ---------------- K4: local stripe distances + DP ----------------
__global__ void local_kernel(const float* __restrict__ centers,
                             const float* __restrict__ localf,
                             const int* __restrict__ pinds,
                             const int* __restrict__ ninds,
                             float* __restrict__ res) { // [2][96]
    const int c = blockIdx.x;
    const int which = blockIdx.y;
    const int tid = threadIdx.x;
    const int idx = (which == 0) ? pinds[c] : ninds[c];

    __shared__ float xl[NS * 1028];
    __shared__ float yl[NS * 1032];
    __shared__ float sred[256];
    __shared__ float dmat[64];
    __shared__ float xx[8], yy[8], xyv[64];

#pragma unroll
    for (int it = 0; it < 8; ++it) {
        const int q = tid + it * 256;
        const float4 v = *(const float4*)&centers[(size_t)c * FD + q * 4];
        const int i = q >> 8;
        const int d = (q * 4) & 1023;
        *(float4*)&xl[i * 1028 + d] = v;

        const float4 w = *(const float4*)&localf[(size_t)idx * FD + q * 4];
        const int jb = (q * 4) & 7;
        const int dd = q >> 1;
        yl[(jb + 0) * 1032 + dd] = w.x;
        yl[(jb + 1) * 1032 + dd] = w.y;
        yl[(jb + 2) * 1032 + dd] = w.z;
        yl[(jb + 3) * 1032 + dd] = w.w;
    }
    __syncthreads();

    const int p = tid >> 2, c4 = tid & 3;
    const int i = p >> 3, j = p & 7;
    float s = 0.f;
    for (int t = 0; t < 64; ++t) {
        const int d = c4 * 4 + t * 16;
        const float4 xv = *(const float4*)&xl[i * 1028 + d];
        const float4 yv = *(const float4*)&yl[j * 1032 + d];
        s += xv.x * yv.x + xv.y * yv.y + xv.z * yv.z + xv.w * yv.w;
    }
    sred[tid] = s;
    __syncthreads();
    if (tid < 64)
        xyv[tid] = sred[tid * 4] + sred[tid * 4 + 1] + sred[tid * 4 + 2] + sred[tid * 4 + 3];

    float s2 = 0.f;
    if (tid < 64) {
        const int r = tid >> 2;
        const float* base = (r < 8) ? &xl[r * 1028] : &yl[(r - 8) * 1032];
        for (int t = 0; t < 64; ++t) {
            const int d = c4 * 4 + t * 16;
            const float4 v = *(const float4*)&base[d];
            s2 += v.x * v.x + v.y * v.y + v.z * v.z + v.w * v.w;
        }
    }
    __syncthreads();
    sred[tid] = s2;
    __syncthreads();
    if (tid < 16) {
        const float v = sred[tid * 4] + sred[tid * 4 + 1] + sred[tid * 4 + 2] + sred[tid * 4 + 3];
        if (tid < 8) xx[tid] = v; else yy[tid - 8] = v;
    }
    __syncthreads();

    if (tid < 64) {
        const float d2 = xx[i] + yy[j] - 2.f * xyv[tid];
        const float d = sqrtf(fmaxf(d2, 1e-12f));
        dmat[tid] = tanhf(0.5f * d);
    }
    __syncthreads();

    if (tid == 0) {
        float prev[8], cur[8];
        cur[0] = dmat[0];
#pragma unroll
        for (int jj = 1; jj < 8; ++jj) cur[jj] = cur[jj - 1] + dmat[jj];
        for (int ii = 1; ii < 8; ++ii) {
#pragma unroll
            for (int jj = 0; jj < 8; ++jj) prev[jj] = cur[jj];
            cur[0] = prev[0] + dmat[ii * 8];
#pragma unroll
            for (int jj = 1; jj < 8; ++jj)
                cur[jj] = fminf(prev[jj], cur[jj - 1]) + dmat[ii * 8 + jj];
        }
        res[which * NC + c] = cur[7];
    }
}

// ---------------- K5: mean(relu(ap - an + margin)) ----------------
__global__ void loss_kernel(const float* __restrict__ res, float* __restrict__ out) {
    const int tid = threadIdx.x; // 128
    float v = 0.f;
    if (tid < NC) v = fmaxf(res[tid] - res[NC + tid] + MARGIN, 0.f);
#pragma unroll
    for (int off = 32; off > 0; off >>= 1) v += __shfl_down(v, off, 64);
    __shared__ float w2[2];
    const int lane = tid & 63, w = tid >> 6;
    if (lane == 0) w2[w] = v;
    __syncthreads();
    if (tid == 0) out[0] = (w2[0] + w2[1]) * (1.f / NC);
}

extern "C" void kernel_launch(void* const* d_in, const int* in_sizes, int n_in,
                              void* d_out, int out_size, void* d_ws, size_t ws_size,
                              hipStream_t stream) {
    const float* feats  = (const float*)d_in[0];
    const int*   labels = (const int*)d_in[1];
    const float* localf = (const float*)d_in[2];
    float* out = (float*)d_out;

    float* centers = (float*)d_ws;                          // 96*8192
    float* part    = centers + (size_t)NC * FD;             // 96*32*1536
    float* fnp     = part + (size_t)NC * KSPLIT * M_ROWS;   // 4*1536
    float* cnp     = fnp + 4 * M_ROWS;                      // 4*96
    float* res     = cnp + 4 * NC;                          // 2*96
    int*   pinds   = (int*)(res + 2 * NC);                  // 96
    int*   ninds   = pinds + NC;                            // 96

    hipLaunchKernelGGL(centers_kernel, dim3(NC, 4), dim3(256), 0, stream,
                       feats, centers, fnp, cnp);
    hipLaunchKernelGGL(gemm10_kernel, dim3(24 * KSPLIT), dim3(256), 0, stream,
                       centers, feats, part);
    hipLaunchKernelGGL(select_kernel, dim3(NC), dim3(256), 0, stream,
                       part, fnp, cnp, labels, pinds, ninds);
    hipLaunchKernelGGL(local_kernel, dim3(NC, 2), dim3(256), 0, stream,
                       centers, localf, pinds, ninds, res);
    hipLaunchKernelGGL(loss_kernel, dim3(1), dim3(128), 0, stream, res, out);
}

// Round 11
// 52.545 us; speedup vs baseline: 18.5750x; 1.0238x over previous
//
#include <hip/hip_runtime.h>
#include <math.h>

#define M_ROWS 1536
#define NC 96
#define KG 16
#define FD 8192
#define NS 8
#define MARGIN 0.3f

#define KSPLIT 32
#define KCH 256            /* k per block */
#define BKS 32             /* k per stage */
#define NST (KCH / BKS)    /* 8 stages */
#define BN 64              /* n cols per block */

typedef short v8s __attribute__((ext_vector_type(8)));   // 8 bf16
typedef float v4f __attribute__((ext_vector_type(4)));

// truncation split: hi = top16(x); lo = top16(x - hi)  (4 ops/float)
// residual <= 2^-16 |x| -> d2 err ~4e-3, selection-safe (gaps O(6)).
__device__ __forceinline__ void split4t(float4 v, ushort4* h, ushort4* l) {
    const unsigned int ux = __float_as_uint(v.x), uy = __float_as_uint(v.y);
    const unsigned int uz = __float_as_uint(v.z), uw = __float_as_uint(v.w);
    *h = make_ushort4((unsigned short)(ux >> 16), (unsigned short)(uy >> 16),
                      (unsigned short)(uz >> 16), (unsigned short)(uw >> 16));
    const float rx = v.x - __uint_as_float(ux & 0xffff0000u);
    const float ry = v.y - __uint_as_float(uy & 0xffff0000u);
    const float rz = v.z - __uint_as_float(uz & 0xffff0000u);
    const float rw = v.w - __uint_as_float(uw & 0xffff0000u);
    *l = make_ushort4((unsigned short)(__float_as_uint(rx) >> 16),
                      (unsigned short)(__float_as_uint(ry) >> 16),
                      (unsigned short)(__float_as_uint(rz) >> 16),
                      (unsigned short)(__float_as_uint(rw) >> 16));
}

// ---------------- K1: centers + squared-norm partials ----------------
__global__ void centers_kernel(const float* __restrict__ feats,
                               float* __restrict__ centers,
                               float* __restrict__ fnp,   // [4][1536]
                               float* __restrict__ cnp) { // [4][96]
    const int c = blockIdx.x;
    const int bd = blockIdx.y;
    const int tid = threadIdx.x;

    float sq[KG];
#pragma unroll
    for (int k = 0; k < KG; ++k) sq[k] = 0.f;
    float cp = 0.f;

#pragma unroll
    for (int it = 0; it < 2; ++it) {
        const int base = bd * 2048 + it * 1024 + tid * 4;
        float4 acc = make_float4(0.f, 0.f, 0.f, 0.f);
#pragma unroll
        for (int k = 0; k < KG; ++k) {
            const float4 v = *(const float4*)&feats[(size_t)(c * KG + k) * FD + base];
            acc.x += v.x; acc.y += v.y; acc.z += v.z; acc.w += v.w;
            sq[k] += v.x * v.x + v.y * v.y + v.z * v.z + v.w * v.w;
        }
        float4 cv = make_float4(acc.x * 0.0625f, acc.y * 0.0625f,
                                acc.z * 0.0625f, acc.w * 0.0625f);
        *(float4*)&centers[(size_t)c * FD + base] = cv;
        cp += cv.x * cv.x + cv.y * cv.y + cv.z * cv.z + cv.w * cv.w;
    }

    const int lane = tid & 63;
    const int w = tid >> 6;
    __shared__ float wred[4][17];
#pragma unroll
    for (int k = 0; k < KG; ++k) {
        float v = sq[k];
#pragma unroll
        for (int off = 32; off > 0; off >>= 1) v += __shfl_down(v, off, 64);
        if (lane == 0) wred[w][k] = v;
    }
    {
        float v = cp;
#pragma unroll
        for (int off = 32; off > 0; off >>= 1) v += __shfl_down(v, off, 64);
        if (lane == 0) wred[w][16] = v;
    }
    __syncthreads();
    if (tid < 17) {
        const float t = wred[0][tid] + wred[1][tid] + wred[2][tid] + wred[3][tid];
        if (tid < 16) fnp[bd * M_ROWS + c * KG + tid] = t;
        else          cnp[bd * NC + c] = t;
    }
}

// ---------------- K2: bf16x3 MFMA partial GEMM ----------------
// 768 blocks = 24 nb x 32 ks (bid%8==ks%8 pins k-slice to one XCD), 4 waves.
// R11: 2x2 wave tiling (wave = 48m x 32n): LDS reads/stage 14 -> 10 b128
// (the binding resource), MFMA count unchanged. Truncation split (4 ops/float
// vs 11). Frag-linear LDS (lane*16B), double-buffered, 1 barrier/stage.
__global__ __launch_bounds__(256) void gemm11_kernel(const float* __restrict__ centers,
                                                     const float* __restrict__ feats,
                                                     float* __restrict__ part) { // [96][32][1536]
    const int bid = blockIdx.x;
    const int ks = bid & 31;
    const int nb = bid >> 5;
    const int tid = threadIdx.x;
    const int j0 = nb * BN;
    const int k0b = ks * KCH;

    __shared__ unsigned short AH[2][6 * 512], AL[2][6 * 512];   // 6 m-tiles
    __shared__ unsigned short BH[2][4 * 512], BL[2][4 * 512];   // 4 n-tiles

    // staging maps: element (row r, k) -> tile r>>4, lane (r&15)|((k>>3)<<4),
    // elem k&7. A thread's 4 consecutive k share (k>>3) -> one ushort4 write.
    int aoff[3], aidx[3];
#pragma unroll
    for (int i = 0; i < 3; ++i) {
        const int q = tid + i * 256;                 // A: 96 rows x 32 k / 4
        const int m = q >> 3, kk = (q & 7) * 4;
        aoff[i] = m * FD + kk;
        aidx[i] = (m >> 4) * 512 + ((m & 15) | ((kk >> 3) << 4)) * 8 + (kk & 7);
    }
    int boff[2], bidx[2];
#pragma unroll
    for (int i = 0; i < 2; ++i) {
        const int q = tid + i * 256;                 // B: 64 rows x 32 k / 4
        const int n = q >> 3, kk = (q & 7) * 4;
        boff[i] = (j0 + n) * FD + kk;
        bidx[i] = (n >> 4) * 512 + ((n & 15) | ((kk >> 3) << 4)) * 8 + (kk & 7);
    }

    float4 pa[3], pb[2];
    // prologue: stage 0 -> buf 0
#pragma unroll
    for (int i = 0; i < 3; ++i) pa[i] = *(const float4*)&centers[aoff[i] + k0b];
#pragma unroll
    for (int i = 0; i < 2; ++i) pb[i] = *(const float4*)&feats[boff[i] + k0b];
#pragma unroll
    for (int i = 0; i < 3; ++i) {
        ushort4 h, l; split4t(pa[i], &h, &l);
        *(ushort4*)&AH[0][aidx[i]] = h; *(ushort4*)&AL[0][aidx[i]] = l;
    }
#pragma unroll
    for (int i = 0; i < 2; ++i) {
        ushort4 h, l; split4t(pb[i], &h, &l);
        *(ushort4*)&BH[0][bidx[i]] = h; *(ushort4*)&BL[0][bidx[i]] = l;
    }
    __syncthreads();

    v4f acc[3][2];
#pragma unroll
    for (int a = 0; a < 3; ++a)
#pragma unroll
        for (int b = 0; b < 2; ++b) {
            acc[a][b][0] = 0.f; acc[a][b][1] = 0.f;
            acc[a][b][2] = 0.f; acc[a][b][3] = 0.f;
        }

    const int w = tid >> 6, lane = tid & 63;
    const int wm = w >> 1, wn = w & 1;      // wave covers m-tiles wm*3..+2, n-tiles wn*2..+1
    const int fo = lane * 8;

    int cur = 0;
    for (int st = 0; st < NST; ++st) {
        // issue next stage's global loads; latency hides under MFMA below
        if (st < NST - 1) {
            const int k0 = k0b + (st + 1) * BKS;
#pragma unroll
            for (int i = 0; i < 3; ++i) pa[i] = *(const float4*)&centers[aoff[i] + k0];
#pragma unroll
            for (int i = 0; i < 2; ++i) pb[i] = *(const float4*)&feats[boff[i] + k0];
        }

        // compute: 2 B-frag pairs + 3 A-frag pairs -> 10 ds_read_b128, 18 MFMA
        v8s Bhf[2], Blf[2];
#pragma unroll
        for (int nt = 0; nt < 2; ++nt) {
            Bhf[nt] = *(const v8s*)&BH[cur][(wn * 2 + nt) * 512 + fo];
            Blf[nt] = *(const v8s*)&BL[cur][(wn * 2 + nt) * 512 + fo];
        }
#pragma unroll
        for (int mt = 0; mt < 3; ++mt) {
            const v8s Ahf = *(const v8s*)&AH[cur][(wm * 3 + mt) * 512 + fo];
            const v8s Alf = *(const v8s*)&AL[cur][(wm * 3 + mt) * 512 + fo];
#pragma unroll
            for (int nt = 0; nt < 2; ++nt) {
                acc[mt][nt] = __builtin_amdgcn_mfma_f32_16x16x32_bf16(Ahf, Bhf[nt], acc[mt][nt], 0, 0, 0);
                acc[mt][nt] = __builtin_amdgcn_mfma_f32_16x16x32_bf16(Ahf, Blf[nt], acc[mt][nt], 0, 0, 0);
                acc[mt][nt] = __builtin_amdgcn_mfma_f32_16x16x32_bf16(Alf, Bhf[nt], acc[mt][nt], 0, 0, 0);
            }
        }

        // convert + write next stage into the other buffer
        if (st < NST - 1) {
            const int d = cur ^ 1;
#pragma unroll
            for (int i = 0; i < 3; ++i) {
                ushort4 h, l; split4t(pa[i], &h, &l);
                *(ushort4*)&AH[d][aidx[i]] = h; *(ushort4*)&AL[d][aidx[i]] = l;
            }
#pragma unroll
            for (int i = 0; i < 2; ++i) {
                ushort4 h, l; split4t(pb[i], &h, &l);
                *(ushort4*)&BH[d][bidx[i]] = h; *(ushort4*)&BL[d][bidx[i]] = l;
            }
        }
        __syncthreads();
        cur ^= 1;
    }

    // epilogue: C/D layout (m89-verified): col = lane&15, row = (lane>>4)*4 + j
    const int col = lane & 15, r0 = (lane >> 4) * 4;
#pragma unroll
    for (int mt = 0; mt < 3; ++mt) {
#pragma unroll
        for (int nt = 0; nt < 2; ++nt) {
            const int n = j0 + (wn * 2 + nt) * 16 + col;
#pragma unroll
            for (int j = 0; j < 4; ++j) {
                const int m = (wm * 3 + mt) * 16 + r0 + j;
                part[((size_t)m * KSPLIT + ks) * M_ROWS + n] = acc[mt][nt][j];
            }
        }
    }
}

// ---------------- K3: finalize d2 + masked argmax/argmin ----------------
__global__ void select_kernel(const float* __restrict__ part,
                              const float* __restrict__ fnp,
                              const float* __restrict__ cnp,
                              const int* __restrict__ labels,
                              int* __restrict__ pinds,
                              int* __restrict__ ninds) {
    const int c = blockIdx.x;
    const int tid = threadIdx.x;
    const int anchor = labels[c * KG];

    float cn = 0.f;
#pragma unroll
    for (int b = 0; b < 4; ++b) cn += cnp[b * NC + c];

    float bestp = -INFINITY; int bpi = 1 << 30;
    float bestn =  INFINITY; int bni = 1 << 30;

    const float* pc = part + (size_t)c * KSPLIT * M_ROWS;
    for (int j = tid; j < M_ROWS; j += 256) {
        float dot = 0.f;
#pragma unroll
        for (int p = 0; p < KSPLIT; ++p)
            dot += pc[(size_t)p * M_ROWS + j];
        float fn = 0.f;
#pragma unroll
        for (int b = 0; b < 4; ++b) fn += fnp[b * M_ROWS + j];
        const float d2 = cn + fn - 2.f * dot;
        const bool pos = (labels[j] == anchor);
        if (pos) {
            if (d2 > bestp || (d2 == bestp && j < bpi)) { bestp = d2; bpi = j; }
        } else {
            if (d2 < bestn || (d2 == bestn && j < bni)) { bestn = d2; bni = j; }
        }
    }

    __shared__ float sv[256];
    __shared__ int   si[256];
    sv[tid] = bestp; si[tid] = bpi; __syncthreads();
    for (int s = 128; s > 0; s >>= 1) {
        if (tid < s) {
            if (sv[tid + s] > sv[tid] ||
                (sv[tid + s] == sv[tid] && si[tid + s] < si[tid])) {
                sv[tid] = sv[tid + s]; si[tid] = si[tid + s];
            }
        }
        __syncthreads();
    }
    if (tid == 0) pinds[c] = si[0];
    __syncthreads();
    sv[tid] = bestn; si[tid] = bni; __syncthreads();
    for (int s = 128; s > 0; s >>= 1) {
        if (tid < s) {
            if (sv[tid + s] < sv[tid] ||
                (sv[tid + s] == sv[tid] && si[tid + s] < si[tid])) {
                sv[tid] = sv[tid + s]; si[tid] = si[tid + s];
            }
        }
        __syncthreads();
    }
    if (tid == 0) ninds[c] = si[0];
}

// ---------------- K4: local stripe distances + DP ----------------
__global__ void local_kernel(const float* __restrict__ centers,
                             const float* __restrict__ localf,
                             const int* __restrict__ pinds,
                             const int* __restrict__ ninds,
                             float* __restrict__ res) { // [2][96]
    const int c = blockIdx.x;
    const int which = blockIdx.y;
    const int tid = threadIdx.x;
    const int idx = (which == 0) ? pinds[c] : ninds[c];

    __shared__ float xl[NS * 1028];
    __shared__ float yl[NS * 1032];
    __shared__ float sred[256];
    __shared__ float dmat[64];
    __shared__ float xx[8], yy[8], xyv[64];

#pragma unroll
    for (int it = 0; it < 8; ++it) {
        const int q = tid + it * 256;
        const float4 v = *(const float4*)&centers[(size_t)c * FD + q * 4];
        const int i = q >> 8;
        const int d = (q * 4) & 1023;
        *(float4*)&xl[i * 1028 + d] = v;

        const float4 w = *(const float4*)&localf[(size_t)idx * FD + q * 4];
        const int jb = (q * 4) & 7;
        const int dd = q >> 1;
        yl[(jb + 0) * 1032 + dd] = w.x;
        yl[(jb + 1) * 1032 + dd] = w.y;
        yl[(jb + 2) * 1032 + dd] = w.z;
        yl[(jb + 3) * 1032 + dd] = w.w;
    }
    __syncthreads();

    const int p = tid >> 2, c4 = tid & 3;
    const int i = p >> 3, j = p & 7;
    float s = 0.f;
    for (int t = 0; t < 64; ++t) {
        const int d = c4 * 4 + t * 16;
        const float4 xv = *(const float4*)&xl[i * 1028 + d];
        const float4 yv = *(const float4*)&yl[j * 1032 + d];
        s += xv.x * yv.x + xv.y * yv.y + xv.z * yv.z + xv.w * yv.w;
    }
    sred[tid] = s;
    __syncthreads();
    if (tid < 64)
        xyv[tid] = sred[tid * 4] + sred[tid * 4 + 1] + sred[tid * 4 + 2] + sred[tid * 4 + 3];

    float s2 = 0.f;
    if (tid < 64) {
        const int r = tid >> 2;
        const float* base = (r < 8) ? &xl[r * 1028] : &yl[(r - 8) * 1032];
        for (int t = 0; t < 64; ++t) {
            const int d = c4 * 4 + t * 16;
            const float4 v = *(const float4*)&base[d];
            s2 += v.x * v.x + v.y * v.y + v.z * v.z + v.w * v.w;
        }
    }
    __syncthreads();
    sred[tid] = s2;
    __syncthreads();
    if (tid < 16) {
        const float v = sred[tid * 4] + sred[tid * 4 + 1] + sred[tid * 4 + 2] + sred[tid * 4 + 3];
        if (tid < 8) xx[tid] = v; else yy[tid - 8] = v;
    }
    __syncthreads();

    if (tid < 64) {
        const float d2 = xx[i] + yy[j] - 2.f * xyv[tid];
        const float d = sqrtf(fmaxf(d2, 1e-12f));
        dmat[tid] = tanhf(0.5f * d);
    }
    __syncthreads();

    if (tid == 0) {
        float prev[8], cur[8];
        cur[0] = dmat[0];
#pragma unroll
        for (int jj = 1; jj < 8; ++jj) cur[jj] = cur[jj - 1] + dmat[jj];
        for (int ii = 1; ii < 8; ++ii) {
#pragma unroll
            for (int jj = 0; jj < 8; ++jj) prev[jj] = cur[jj];
            cur[0] = prev[0] + dmat[ii * 8];
#pragma unroll
            for (int jj = 1; jj < 8; ++jj)
                cur[jj] = fminf(prev[jj], cur[jj - 1]) + dmat[ii * 8 + jj];
        }
        res[which * NC + c] = cur[7];
    }
}

// ---------------- K5: mean(relu(ap - an + margin)) ----------------
__global__ void loss_kernel(const float* __restrict__ res, float* __restrict__ out) {
    const int tid = threadIdx.x; // 128
    float v = 0.f;
    if (tid < NC) v = fmaxf(res[tid] - res[NC + tid] + MARGIN, 0.f);
#pragma unroll
    for (int off = 32; off > 0; off >>= 1) v += __shfl_down(v, off, 64);
    __shared__ float w2[2];
    const int lane = tid & 63, w = tid >> 6;
    if (lane == 0) w2[w] = v;
    __syncthreads();
    if (tid == 0) out[0] = (w2[0] + w2[1]) * (1.f / NC);
}

extern "C" void kernel_launch(void* const* d_in, const int* in_sizes, int n_in,
                              void* d_out, int out_size, void* d_ws, size_t ws_size,
                              hipStream_t stream) {
    const float* feats  = (const float*)d_in[0];
    const int*   labels = (const int*)d_in[1];
    const float* localf = (const float*)d_in[2];
    float* out = (float*)d_out;

    float* centers = (float*)d_ws;                          // 96*8192
    float* part    = centers + (size_t)NC * FD;             // 96*32*1536
    float* fnp     = part + (size_t)NC * KSPLIT * M_ROWS;   // 4*1536
    float* cnp     = fnp + 4 * M_ROWS;                      // 4*96
    float* res     = cnp + 4 * NC;                          // 2*96
    int*   pinds   = (int*)(res + 2 * NC);                  // 96
    int*   ninds   = pinds + NC;                            // 96

    hipLaunchKernelGGL(centers_kernel, dim3(NC, 4), dim3(256), 0, stream,
                       feats, centers, fnp, cnp);
    hipLaunchKernelGGL(gemm11_kernel, dim3(24 * KSPLIT), dim3(256), 0, stream,
                       centers, feats, part);
    hipLaunchKernelGGL(select_kernel, dim3(NC), dim3(256), 0, stream,
                       part, fnp, cnp, labels, pinds, ninds);
    hipLaunchKernelGGL(local_kernel, dim3(NC, 2), dim3(256), 0, stream,
                       centers, localf, pinds, ninds, res);
    hipLaunchKernelGGL(loss_kernel, dim3(1), dim3(128), 0, stream, res, out);
}